// Round 3
// baseline (693.448 us; speedup 1.0000x reference)
//
#include <hip/hip_runtime.h>

// ---------------------------------------------------------------------------
// MultiHeadAttention_patch2: B*C = 262144 independent 4-token, 55-dim attns.
// All I/O is float32 (per the reference file's dtypes).
// Key identity (heads never split):
//   attn = softmax( xr M1 xr^T ),  M1 = scale * Wq^T Wk   (55x55)
//   out  = attn (xr P) + b,        P  = Wv^T Wfc^T        (55x55)
// Each sequence's 220 floats are contiguous in x; rearrange is a fixed
// permutation: local = p1*110 + p2*5 + h*10 + w,  token t=(p1,p2), d=(h,w).
// ---------------------------------------------------------------------------

// DPP quad-perm broadcast of lane j within each group of 4 lanes.
// update_dpp with defined old (0) + bound_ctrl: fully-defined semantics.
#define QB(v, ctrl) __int_as_float(__builtin_amdgcn_update_dpp( \
    0, __float_as_int(v), (ctrl), 0xf, 0xf, true))

// ws layout (fp32): [0,3025) M1T[dp][d], [3025,6050) PT[dp][d], [6050,6105) bias
__global__ void setup_weights(const float* __restrict__ wq,
                              const float* __restrict__ wk,
                              const float* __restrict__ wv,
                              const float* __restrict__ wfc,
                              const float* __restrict__ bfc,
                              float* __restrict__ ws) {
    int i = blockIdx.x * blockDim.x + threadIdx.x;
    if (i < 3025) {
        int dp = i / 55, d = i % 55;
        float m1 = 0.f, p = 0.f;
        for (int e = 0; e < 48; ++e) {
            m1 += wq[e * 55 + d] * wk[e * 55 + dp];
            p  += wv[e * 55 + d] * wfc[dp * 48 + e];
        }
        ws[dp * 55 + d]        = m1 * 0.14433756729740643f; // 1/sqrt(48)
        ws[3025 + dp * 55 + d] = p;
    }
    if (i < 55) ws[6050 + i] = bfc[i];
}

__global__ void __launch_bounds__(128)
attn_main(const float* __restrict__ x,
          const float* __restrict__ ws,
          float* __restrict__ out) {
    __shared__ __align__(16) float lds[32 * 220]; // 28160 B
    const float* __restrict__ M1T = ws;
    const float* __restrict__ PT  = ws + 3025;
    const float* __restrict__ BS  = ws + 6050;

    const int tid = threadIdx.x;
    const size_t seq0 = (size_t)blockIdx.x * 32;
    const float* __restrict__ xb = x + seq0 * 220;
    float* __restrict__ ob = out + seq0 * 220;

    // ---- stage 32 sequences (contiguous 28160 B) into LDS, vectorized ----
    {
        const uint4* __restrict__ src = (const uint4*)xb;
        uint4* dst = (uint4*)lds;
        #pragma unroll
        for (int it = 0; it < 14; ++it) {
            int i = tid + it * 128;
            if (i < 1760) dst[i] = src[i];
        }
    }
    __syncthreads();

    // thread = one token: lane-quad holds the 4 tokens of one sequence
    const int t      = tid & 3;
    const int sl     = tid >> 2;
    const int tokoff = (t >> 1) * 110 + (t & 1) * 5;
    const int base   = sl * 220 + tokoff;

    // own token's 55 features -> registers, permuted order d = h*5+w
    float xreg[55];
    #pragma unroll
    for (int d = 0; d < 55; ++d) {
        const int doff = (d / 5) * 10 + (d % 5);
        xreg[d] = lds[base + doff];
    }

    // ---- phase A: attn logits la[t'] = sum_dp (xr[t]·M1T[dp]) * xr[t'][dp]
    float la0 = 0.f, la1 = 0.f, la2 = 0.f, la3 = 0.f;
    for (int h = 0; h < 11; ++h) {
        for (int w = 0; w < 5; ++w) {
            const int dp = h * 5 + w;
            const float* __restrict__ m = M1T + dp * 55; // wave-uniform
            float a0 = 0.f, a1 = 0.f, a2 = 0.f, a3 = 0.f;
            #pragma unroll
            for (int d = 0; d < 52; d += 4) {
                a0 = fmaf(xreg[d + 0], m[d + 0], a0);
                a1 = fmaf(xreg[d + 1], m[d + 1], a1);
                a2 = fmaf(xreg[d + 2], m[d + 2], a2);
                a3 = fmaf(xreg[d + 3], m[d + 3], a3);
            }
            a0 = fmaf(xreg[52], m[52], a0);
            a1 = fmaf(xreg[53], m[53], a1);
            a2 = fmaf(xreg[54], m[54], a2);
            const float t1 = (a0 + a1) + (a2 + a3);
            const float xc = xreg[dp]; // own xr[t][dp]
            la0 = fmaf(t1, QB(xc, 0x00), la0);
            la1 = fmaf(t1, QB(xc, 0x55), la1);
            la2 = fmaf(t1, QB(xc, 0xAA), la2);
            la3 = fmaf(t1, QB(xc, 0xFF), la3);
        }
    }

    // ---- softmax over the 4 logits ----
    const float mx = fmaxf(fmaxf(la0, la1), fmaxf(la2, la3));
    const float e0 = __expf(la0 - mx), e1 = __expf(la1 - mx);
    const float e2 = __expf(la2 - mx), e3 = __expf(la3 - mx);
    const float inv = 1.0f / (e0 + e1 + e2 + e3);
    const float p0 = e0 * inv, p1 = e1 * inv, p2 = e2 * inv, p3 = e3 * inv;

    __syncthreads(); // phase B overwrites the LDS x buffer with outputs

    // ---- phase B: out[t][dp] = b[dp] + sum_t' p[t'] * (xr[t']·PT[dp]) ----
    for (int h = 0; h < 11; ++h) {
        for (int w = 0; w < 5; ++w) {
            const int dp = h * 5 + w;
            const float* __restrict__ pc = PT + dp * 55; // wave-uniform
            float a0 = 0.f, a1 = 0.f, a2 = 0.f, a3 = 0.f;
            #pragma unroll
            for (int d = 0; d < 52; d += 4) {
                a0 = fmaf(xreg[d + 0], pc[d + 0], a0);
                a1 = fmaf(xreg[d + 1], pc[d + 1], a1);
                a2 = fmaf(xreg[d + 2], pc[d + 2], a2);
                a3 = fmaf(xreg[d + 3], pc[d + 3], a3);
            }
            a0 = fmaf(xreg[52], pc[52], a0);
            a1 = fmaf(xreg[53], pc[53], a1);
            a2 = fmaf(xreg[54], pc[54], a2);
            const float t2 = (a0 + a1) + (a2 + a3); // T2[own t][dp]
            float o = BS[dp];
            o = fmaf(p0, QB(t2, 0x00), o);
            o = fmaf(p1, QB(t2, 0x55), o);
            o = fmaf(p2, QB(t2, 0xAA), o);
            o = fmaf(p3, QB(t2, 0xFF), o);
            lds[base + h * 10 + w] = o;
        }
    }
    __syncthreads();

    // ---- store 32 sequences back, vectorized ----
    {
        const uint4* __restrict__ src = (const uint4*)lds;
        uint4* dst = (uint4*)ob;
        #pragma unroll
        for (int it = 0; it < 14; ++it) {
            int i = tid + it * 128;
            if (i < 1760) dst[i] = src[i];
        }
    }
}

extern "C" void kernel_launch(void* const* d_in, const int* in_sizes, int n_in,
                              void* d_out, int out_size, void* d_ws, size_t ws_size,
                              hipStream_t stream) {
    const float* x   = (const float*)d_in[0];
    const float* wq  = (const float*)d_in[1];
    const float* wk  = (const float*)d_in[2];
    const float* wv  = (const float*)d_in[3];
    const float* wfc = (const float*)d_in[4];
    const float* bfc = (const float*)d_in[5];
    float* ws = (float*)d_ws; // needs 6105 floats = 24420 B

    const int nseq = out_size / 220;   // 262144
    const int nblk = nseq / 32;        // 8192

    hipLaunchKernelGGL(setup_weights, dim3(12), dim3(256), 0, stream,
                       wq, wk, wv, wfc, bfc, ws);
    hipLaunchKernelGGL(attn_main, dim3(nblk), dim3(128), 0, stream,
                       x, ws, (float*)d_out);
}